// Round 1
// baseline (127.681 us; speedup 1.0000x reference)
//
#include <hip/hip_runtime.h>
#include <hip/hip_bf16.h>

#define N_IMG 2048
#define K_TXT 128
#define D_IN  768
#define H_DIM 512
#define M_TOT (N_IMG + K_TXT)   // 2176 virtual rows (img ++ txt)

typedef __bf16 bf16x8 __attribute__((ext_vector_type(8)));
typedef float  f32x4  __attribute__((ext_vector_type(4)));

// ---------------------------------------------------------------------------
// Kernel 1: P[r][h] = X[r] @ W1half  (+ b1 for txt rows), bf16 MFMA, fp32 out.
// Block tile 64m x 64n, BK=32 (one 16x16x32 MFMA k-step), 4 waves as 2x2.
// ---------------------------------------------------------------------------
__global__ __launch_bounds__(256) void proj_kernel(
    const float* __restrict__ img, const float* __restrict__ txt,
    const float* __restrict__ W1, const float* __restrict__ b1,
    float* __restrict__ P)
{
    __shared__ __align__(16) __bf16 As[64][40];  // [m][k] row stride 80B (=5*16B)
    __shared__ __align__(16) __bf16 Bs[64][40];  // [n][k]

    const int tid = threadIdx.x;
    const int n0 = blockIdx.x * 64;
    const int m0 = blockIdx.y * 64;
    const bool is_txt = (m0 >= N_IMG);
    const float* X  = is_txt ? (txt + (size_t)(m0 - N_IMG) * D_IN)
                             : (img + (size_t)m0 * D_IN);
    const float* Wb = W1 + (is_txt ? (size_t)D_IN * H_DIM : 0);

    const int wave = tid >> 6, lane = tid & 63;
    const int wm = (wave >> 1) * 32, wn = (wave & 1) * 32;
    const int quad = lane >> 4, lm = lane & 15;

    // staging mappings
    const int am  = tid >> 2, akq = tid & 3;   // A: row am, 8 k at akq*8
    const int bn  = tid & 63, bkq = tid >> 6;  // B: col bn, 8 k-rows at bkq*8

    f32x4 acc[2][2] = {};

    union BPack { __bf16 h[8]; uint4 u; };

    for (int kc = 0; kc < D_IN; kc += 32) {
        // ---- stage A: 8 consecutive fp32 -> bf16, one 16B LDS store
        const float* ap = X + (size_t)am * D_IN + kc + akq * 8;
        f32x4 a0 = *(const f32x4*)ap;
        f32x4 a1 = *(const f32x4*)(ap + 4);
        BPack pa;
        pa.h[0]=(__bf16)a0[0]; pa.h[1]=(__bf16)a0[1]; pa.h[2]=(__bf16)a0[2]; pa.h[3]=(__bf16)a0[3];
        pa.h[4]=(__bf16)a1[0]; pa.h[5]=(__bf16)a1[1]; pa.h[6]=(__bf16)a1[2]; pa.h[7]=(__bf16)a1[3];
        *(uint4*)&As[am][akq * 8] = pa.u;

        // ---- stage B: 8 k-strided scalar loads (coalesced across n-lanes)
        BPack pb;
        #pragma unroll
        for (int j = 0; j < 8; ++j)
            pb.h[j] = (__bf16)Wb[(size_t)(kc + bkq * 8 + j) * H_DIM + n0 + bn];
        *(uint4*)&Bs[bn][bkq * 8] = pb.u;

        __syncthreads();

        bf16x8 af0 = *(bf16x8*)&As[wm +  0 + lm][quad * 8];
        bf16x8 af1 = *(bf16x8*)&As[wm + 16 + lm][quad * 8];
        bf16x8 bf0 = *(bf16x8*)&Bs[wn +  0 + lm][quad * 8];
        bf16x8 bf1 = *(bf16x8*)&Bs[wn + 16 + lm][quad * 8];

        acc[0][0] = __builtin_amdgcn_mfma_f32_16x16x32_bf16(af0, bf0, acc[0][0], 0, 0, 0);
        acc[0][1] = __builtin_amdgcn_mfma_f32_16x16x32_bf16(af0, bf1, acc[0][1], 0, 0, 0);
        acc[1][0] = __builtin_amdgcn_mfma_f32_16x16x32_bf16(af1, bf0, acc[1][0], 0, 0, 0);
        acc[1][1] = __builtin_amdgcn_mfma_f32_16x16x32_bf16(af1, bf1, acc[1][1], 0, 0, 0);

        __syncthreads();
    }

    // epilogue: C/D layout col=lane&15, row=quad*4+r  [m89-verified]
    #pragma unroll
    for (int i = 0; i < 2; ++i) {
        #pragma unroll
        for (int j = 0; j < 2; ++j) {
            const int gn = n0 + wn + j * 16 + lm;
            const float badd = is_txt ? b1[gn] : 0.0f;
            #pragma unroll
            for (int r = 0; r < 4; ++r) {
                const int gm = m0 + wm + i * 16 + quad * 4 + r;
                P[(size_t)gm * H_DIM + gn] = acc[i][j][r] + badd;
            }
        }
    }
}

// ---------------------------------------------------------------------------
// Kernel 2a: pw[r] = 0.5 * dot(P[r], W2)   (one wave per row)
// ---------------------------------------------------------------------------
__global__ __launch_bounds__(256) void pw_kernel(
    const float* __restrict__ P, const float* __restrict__ W2,
    float* __restrict__ pw)
{
    const int row  = blockIdx.x * 4 + (threadIdx.x >> 6);
    const int lane = threadIdx.x & 63;
    const float* p = P + (size_t)row * H_DIM;
    float acc = 0.f;
    #pragma unroll
    for (int base = 0; base < H_DIM; base += 256) {
        f32x4 pv = *(const f32x4*)(p  + base + lane * 4);
        f32x4 wv = *(const f32x4*)(W2 + base + lane * 4);
        acc += pv[0]*wv[0] + pv[1]*wv[1] + pv[2]*wv[2] + pv[3]*wv[3];
    }
    #pragma unroll
    for (int off = 32; off > 0; off >>= 1) acc += __shfl_down(acc, off, 64);
    if (lane == 0) pw[row] = 0.5f * acc;
}

// ---------------------------------------------------------------------------
// Kernel 2b: out[n,k] = pw[n] + pw[N+k] + b2   (the linear half of relu)
// ---------------------------------------------------------------------------
__global__ __launch_bounds__(256) void init_kernel(
    const float* __restrict__ pw, const float* __restrict__ b2,
    float* __restrict__ out)
{
    const int idx = blockIdx.x * 256 + threadIdx.x;   // f4 index, 65536 total
    const int n  = idx >> 5;
    const int k4 = (idx & 31) * 4;
    const float pn = pw[n];
    f32x4 pk = *(const f32x4*)(pw + N_IMG + k4);
    const float b = b2[0];
    f32x4 o;
    o[0] = pn + pk[0] + b; o[1] = pn + pk[1] + b;
    o[2] = pn + pk[2] + b; o[3] = pn + pk[3] + b;
    *(f32x4*)(out + (size_t)n * K_TXT + k4) = o;
}

// ---------------------------------------------------------------------------
// Kernel 3: out[n,k] += sum_h |P_img[n,h] + P_txt[k,h]| * (0.5*W2[h])
// Block: 128n x 64k x 64h slab; thread micro-tile 8n x 4k; h-split via grid.z.
// ---------------------------------------------------------------------------
__global__ __launch_bounds__(256) void sim_kernel(
    const float* __restrict__ P, const float* __restrict__ W2,
    float* __restrict__ out)
{
    __shared__ __align__(16) float As[128][68];  // [n][h], stride 272B = 17*16B
    __shared__ __align__(16) float Bs[64][68];   // [h][k] (transposed)
    __shared__ __align__(16) float Ws[64];

    const int tid = threadIdx.x;
    const int n0 = blockIdx.x * 128;
    const int k0 = blockIdx.y * 64;
    const int hc = blockIdx.z * 64;

    // stage A slab: 128 rows x 64 h, f4 loads
    #pragma unroll
    for (int i = 0; i < 8; ++i) {
        const int flat = tid + i * 256;
        const int row = flat >> 4, c4 = flat & 15;
        f32x4 v = *(const f32x4*)(P + (size_t)(n0 + row) * H_DIM + hc + c4 * 4);
        *(f32x4*)&As[row][c4 * 4] = v;
    }
    // stage B slab transposed: coalesced h-reads (lanes->h), f4 store over k
    {
        const int ht = tid & 63;
        const int kq = tid >> 6;
        #pragma unroll
        for (int i = 0; i < 4; ++i) {
            const int kb = (kq + i * 4) * 4;   // 0,16,32,48 (+kq*4)
            f32x4 v;
            #pragma unroll
            for (int j = 0; j < 4; ++j)
                v[j] = P[(size_t)(N_IMG + k0 + kb + j) * H_DIM + hc + ht];
            *(f32x4*)&Bs[ht][kb] = v;
        }
    }
    if (tid < 16) {
        f32x4 w = *(const f32x4*)(W2 + hc + tid * 4);
        w *= 0.5f;
        *(f32x4*)&Ws[tid * 4] = w;
    }
    __syncthreads();

    const int tx = tid & 15;   // k-dir: 4 k each
    const int ty = tid >> 4;   // n-dir: 8 n each
    float acc[8][4] = {};

    #pragma unroll 4
    for (int h4 = 0; h4 < 16; ++h4) {
        f32x4 w = *(f32x4*)&Ws[h4 * 4];
        f32x4 a[8], b[4];
        #pragma unroll
        for (int i = 0; i < 8; ++i) a[i] = *(f32x4*)&As[ty * 8 + i][h4 * 4];
        #pragma unroll
        for (int jh = 0; jh < 4; ++jh) b[jh] = *(f32x4*)&Bs[h4 * 4 + jh][tx * 4];

        #pragma unroll
        for (int jh = 0; jh < 4; ++jh) {
            const float wv = w[jh];
            #pragma unroll
            for (int i = 0; i < 8; ++i) {
                const float av = a[i][jh];
                #pragma unroll
                for (int jk = 0; jk < 4; ++jk) {
                    const float t = av + b[jh][jk];          // v_add_f32
                    acc[i][jk] = fmaf(fabsf(t), wv, acc[i][jk]); // v_fma w/ |.| mod
                }
            }
        }
    }

    #pragma unroll
    for (int i = 0; i < 8; ++i) {
        const int n = n0 + ty * 8 + i;
        #pragma unroll
        for (int jk = 0; jk < 4; ++jk) {
            const int k = k0 + tx * 4 + jk;
            atomicAdd(&out[(size_t)n * K_TXT + k], acc[i][jk]);
        }
    }
}

// ---------------------------------------------------------------------------
extern "C" void kernel_launch(void* const* d_in, const int* in_sizes, int n_in,
                              void* d_out, int out_size, void* d_ws, size_t ws_size,
                              hipStream_t stream) {
    const float* img = (const float*)d_in[0];
    const float* txt = (const float*)d_in[1];
    const float* W1  = (const float*)d_in[2];
    const float* b1  = (const float*)d_in[3];
    const float* W2  = (const float*)d_in[4];
    const float* b2  = (const float*)d_in[5];
    float* out = (float*)d_out;

    float* P  = (float*)d_ws;                 // 2176 x 512 fp32 = 4.46 MB
    float* pw = P + (size_t)M_TOT * H_DIM;    // 2176 fp32

    proj_kernel<<<dim3(H_DIM / 64, M_TOT / 64), 256, 0, stream>>>(img, txt, W1, b1, P);
    pw_kernel  <<<dim3(M_TOT / 4),              256, 0, stream>>>(P, W2, pw);
    init_kernel<<<dim3((N_IMG * K_TXT / 4) / 256), 256, 0, stream>>>(pw, b2, out);
    sim_kernel <<<dim3(N_IMG / 128, K_TXT / 64, H_DIM / 64), 256, 0, stream>>>(P, W2, out);
}

// Round 2
// 105.716 us; speedup vs baseline: 1.2078x; 1.2078x over previous
//
#include <hip/hip_runtime.h>
#include <hip/hip_bf16.h>

#define N_IMG 2048
#define K_TXT 128
#define D_IN  768
#define H_DIM 512
#define M_TOT (N_IMG + K_TXT)   // 2176 virtual rows (img ++ txt)
#define NK    (N_IMG * K_TXT)   // 262144 outputs

typedef __bf16 bf16x8 __attribute__((ext_vector_type(8)));
typedef float  f32x4  __attribute__((ext_vector_type(4)));

// ---------------------------------------------------------------------------
// Kernel 1: P[r][h] = X[r] @ W1half  (+ b1 for txt rows), bf16 MFMA, fp32 out.
// 64m x 64n tile, BK=64 (2 MFMA k-steps/stage), register-prefetch pipeline.
// LDS: two unpadded [64][32] bf16 buffers per operand (m97 conflict-optimal).
// ---------------------------------------------------------------------------
__global__ __launch_bounds__(256) void proj_kernel(
    const float* __restrict__ img, const float* __restrict__ txt,
    const float* __restrict__ W1, const float* __restrict__ b1,
    float* __restrict__ P)
{
    __shared__ __align__(16) __bf16 As[2][64][32];
    __shared__ __align__(16) __bf16 Bs[2][64][32];

    const int tid = threadIdx.x;
    const int n0 = blockIdx.x * 64;
    const int m0 = blockIdx.y * 64;
    const bool is_txt = (m0 >= N_IMG);
    const float* X  = is_txt ? (txt + (size_t)(m0 - N_IMG) * D_IN)
                             : (img + (size_t)m0 * D_IN);
    const float* Wb = W1 + (is_txt ? (size_t)D_IN * H_DIM : 0);

    const int wave = tid >> 6, lane = tid & 63;
    const int wm = (wave >> 1) * 32, wn = (wave & 1) * 32;
    const int quad = lane >> 4, lm = lane & 15;

    // staging maps
    const int ar  = tid >> 2, akq = tid & 3;   // A: row ar, 16 floats at akq*16
    const int bn  = tid & 63, bq  = tid >> 6;  // B: col bn, k-octets at bq*8

    f32x4 acc[2][2] = {};

    f32x4 aR[4];
    float bR[16];

    auto loadA = [&](int kc) {
        const float* ap = X + (size_t)ar * D_IN + kc + akq * 16;
        aR[0] = *(const f32x4*)(ap + 0);
        aR[1] = *(const f32x4*)(ap + 4);
        aR[2] = *(const f32x4*)(ap + 8);
        aR[3] = *(const f32x4*)(ap + 12);
    };
    auto loadB = [&](int kc) {
        #pragma unroll
        for (int j2 = 0; j2 < 2; ++j2)
            #pragma unroll
            for (int j = 0; j < 8; ++j)
                bR[j2 * 8 + j] =
                    Wb[(size_t)(kc + j2 * 32 + bq * 8 + j) * H_DIM + n0 + bn];
    };

    union BPack { __bf16 h[8]; uint4 u; };

    loadA(0); loadB(0);

    for (int it = 0; it < 12; ++it) {
        // ---- store prefetched regs to LDS (fp32 -> bf16)
        {
            const int sub = akq >> 1, off = (akq & 1) * 16;
            BPack p0, p1;
            #pragma unroll
            for (int j = 0; j < 4; ++j) { p0.h[j] = (__bf16)aR[0][j]; p0.h[4+j] = (__bf16)aR[1][j]; }
            #pragma unroll
            for (int j = 0; j < 4; ++j) { p1.h[j] = (__bf16)aR[2][j]; p1.h[4+j] = (__bf16)aR[3][j]; }
            *(uint4*)&As[sub][ar][off]     = p0.u;
            *(uint4*)&As[sub][ar][off + 8] = p1.u;
            BPack q0, q1;
            #pragma unroll
            for (int j = 0; j < 8; ++j) { q0.h[j] = (__bf16)bR[j]; q1.h[j] = (__bf16)bR[8 + j]; }
            *(uint4*)&Bs[0][bn][bq * 8] = q0.u;
            *(uint4*)&Bs[1][bn][bq * 8] = q1.u;
        }
        __syncthreads();

        if (it < 11) { loadA((it + 1) * 64); loadB((it + 1) * 64); }

        #pragma unroll
        for (int sub = 0; sub < 2; ++sub) {
            bf16x8 af0 = *(bf16x8*)&As[sub][wm +  0 + lm][quad * 8];
            bf16x8 af1 = *(bf16x8*)&As[sub][wm + 16 + lm][quad * 8];
            bf16x8 bf0 = *(bf16x8*)&Bs[sub][wn +  0 + lm][quad * 8];
            bf16x8 bf1 = *(bf16x8*)&Bs[sub][wn + 16 + lm][quad * 8];
            acc[0][0] = __builtin_amdgcn_mfma_f32_16x16x32_bf16(af0, bf0, acc[0][0], 0, 0, 0);
            acc[0][1] = __builtin_amdgcn_mfma_f32_16x16x32_bf16(af0, bf1, acc[0][1], 0, 0, 0);
            acc[1][0] = __builtin_amdgcn_mfma_f32_16x16x32_bf16(af1, bf0, acc[1][0], 0, 0, 0);
            acc[1][1] = __builtin_amdgcn_mfma_f32_16x16x32_bf16(af1, bf1, acc[1][1], 0, 0, 0);
        }
        __syncthreads();
    }

    // epilogue: C/D layout col=lane&15, row=quad*4+r  [m89-verified]
    #pragma unroll
    for (int i = 0; i < 2; ++i) {
        #pragma unroll
        for (int j = 0; j < 2; ++j) {
            const int gn = n0 + wn + j * 16 + lm;
            const float badd = is_txt ? b1[gn] : 0.0f;
            #pragma unroll
            for (int r = 0; r < 4; ++r) {
                const int gm = m0 + wm + i * 16 + quad * 4 + r;
                P[(size_t)gm * H_DIM + gn] = acc[i][j][r] + badd;
            }
        }
    }
}

// ---------------------------------------------------------------------------
// Kernel 2: pw[r] = 0.5 * dot(P[r], W2)   (one wave per row)
// ---------------------------------------------------------------------------
__global__ __launch_bounds__(256) void pw_kernel(
    const float* __restrict__ P, const float* __restrict__ W2,
    float* __restrict__ pw)
{
    const int row  = blockIdx.x * 4 + (threadIdx.x >> 6);
    const int lane = threadIdx.x & 63;
    const float* p = P + (size_t)row * H_DIM;
    float acc = 0.f;
    #pragma unroll
    for (int base = 0; base < H_DIM; base += 256) {
        f32x4 pv = *(const f32x4*)(p  + base + lane * 4);
        f32x4 wv = *(const f32x4*)(W2 + base + lane * 4);
        acc += pv[0]*wv[0] + pv[1]*wv[1] + pv[2]*wv[2] + pv[3]*wv[3];
    }
    #pragma unroll
    for (int off = 32; off > 0; off >>= 1) acc += __shfl_down(acc, off, 64);
    if (lane == 0) pw[row] = 0.5f * acc;
}

// ---------------------------------------------------------------------------
// Kernel 3: P2[hs][n][k] = sum_{h in slab hs} |P_img[n,h] + P_txt[k,h]| * 0.5*W2[h]
// Tile 32n x 64k x 64h; grid 64x2x8 = 1024 blocks (4/CU). Plain f32x4 stores.
// Bs[64][67]: 4-row lane stride = 268 words = 12 mod 32 -> conflict-free.
// ---------------------------------------------------------------------------
__global__ __launch_bounds__(256) void sim_kernel(
    const float* __restrict__ P, const float* __restrict__ W2,
    float* __restrict__ P2)
{
    __shared__ __align__(16) float Bs[64][67];
    __shared__ __align__(16) float Ws[64];

    const int tid = threadIdx.x;
    const int n0 = blockIdx.x * 32;
    const int k0 = blockIdx.y * 64;
    const int hs = blockIdx.z;
    const int hc = hs * 64;

    // stage txt slab: rows k0..k0+63, cols hc..hc+63  (f32x4 copies, no transpose)
    #pragma unroll
    for (int i = 0; i < 4; ++i) {
        const int flat = tid + i * 256;
        const int row = flat >> 4, c4 = flat & 15;
        f32x4 v = *(const f32x4*)(P + (size_t)(N_IMG + k0 + row) * H_DIM + hc + c4 * 4);
        *(f32x4*)&Bs[row][c4 * 4] = v;
    }
    if (tid < 16) {
        f32x4 w = *(const f32x4*)(W2 + hc + tid * 4);
        w *= 0.5f;
        *(f32x4*)&Ws[tid * 4] = w;
    }
    __syncthreads();

    const int tx = tid & 15;   // k: 4 consecutive
    const int ty = tid >> 4;   // n: 2 consecutive rows
    const float* pA = P + (size_t)(n0 + ty * 2) * H_DIM + hc;

    f32x4 acc0 = {0.f, 0.f, 0.f, 0.f};
    f32x4 acc1 = {0.f, 0.f, 0.f, 0.f};

    #pragma unroll 4
    for (int h4 = 0; h4 < 16; ++h4) {
        f32x4 a0 = *(const f32x4*)(pA + h4 * 4);
        f32x4 a1 = *(const f32x4*)(pA + H_DIM + h4 * 4);
        f32x4 w  = *(f32x4*)&Ws[h4 * 4];
        f32x4 b[4];
        #pragma unroll
        for (int j = 0; j < 4; ++j) b[j] = *(f32x4*)&Bs[tx * 4 + j][h4 * 4];

        #pragma unroll
        for (int j = 0; j < 4; ++j) {
            #pragma unroll
            for (int hh = 0; hh < 4; ++hh) {
                const float t0 = a0[hh] + b[j][hh];
                acc0[j] = fmaf(fabsf(t0), w[hh], acc0[j]);
                const float t1 = a1[hh] + b[j][hh];
                acc1[j] = fmaf(fabsf(t1), w[hh], acc1[j]);
            }
        }
    }

    float* o = P2 + (size_t)hs * NK + (size_t)(n0 + ty * 2) * K_TXT + k0 + tx * 4;
    *(f32x4*)o = acc0;
    *(f32x4*)(o + K_TXT) = acc1;
}

// ---------------------------------------------------------------------------
// Kernel 4: out[n,k] = pw[n] + pw[N+k] + b2 + sum_{hs<8} P2[hs][n][k]
// ---------------------------------------------------------------------------
__global__ __launch_bounds__(256) void reduce_kernel(
    const float* __restrict__ P2, const float* __restrict__ pw,
    const float* __restrict__ b2, float* __restrict__ out)
{
    const int idx = blockIdx.x * 256 + threadIdx.x;   // f32x4 index, 65536 total
    const int n  = idx >> 5;
    const int k4 = (idx & 31) * 4;
    const size_t base = (size_t)n * K_TXT + k4;

    f32x4 s = {0.f, 0.f, 0.f, 0.f};
    #pragma unroll
    for (int hs = 0; hs < 8; ++hs)
        s += *(const f32x4*)(P2 + (size_t)hs * NK + base);

    const float add = pw[n] + b2[0];
    f32x4 pk = *(const f32x4*)(pw + N_IMG + k4);
    s[0] += add + pk[0]; s[1] += add + pk[1];
    s[2] += add + pk[2]; s[3] += add + pk[3];
    *(f32x4*)(out + base) = s;
}

// ---------------------------------------------------------------------------
extern "C" void kernel_launch(void* const* d_in, const int* in_sizes, int n_in,
                              void* d_out, int out_size, void* d_ws, size_t ws_size,
                              hipStream_t stream) {
    const float* img = (const float*)d_in[0];
    const float* txt = (const float*)d_in[1];
    const float* W1  = (const float*)d_in[2];
    const float* b1  = (const float*)d_in[3];
    const float* W2  = (const float*)d_in[4];
    const float* b2  = (const float*)d_in[5];
    float* out = (float*)d_out;

    float* P  = (float*)d_ws;                 // 2176 x 512 fp32 = 4.46 MB
    float* pw = P + (size_t)M_TOT * H_DIM;    // 2176 fp32
    float* P2 = pw + M_TOT;                   // 8 x 2048 x 128 fp32 = 8.4 MB

    proj_kernel  <<<dim3(H_DIM / 64, M_TOT / 64), 256, 0, stream>>>(img, txt, W1, b1, P);
    pw_kernel    <<<dim3(M_TOT / 4),              256, 0, stream>>>(P, W2, pw);
    sim_kernel   <<<dim3(N_IMG / 32, K_TXT / 64, H_DIM / 64), 256, 0, stream>>>(P, W2, P2);
    reduce_kernel<<<dim3(NK / 4 / 256),           256, 0, stream>>>(P2, pw, b2, out);
}

// Round 4
// 101.690 us; speedup vs baseline: 1.2556x; 1.0396x over previous
//
#include <hip/hip_runtime.h>
#include <hip/hip_bf16.h>

#define N_IMG 2048
#define K_TXT 128
#define D_IN  768
#define H_DIM 512
#define M_TOT (N_IMG + K_TXT)   // 2176 virtual rows (img ++ txt)
#define NK    (N_IMG * K_TXT)   // 262144 outputs

typedef __bf16 bf16x8 __attribute__((ext_vector_type(8)));
typedef float  f32x4  __attribute__((ext_vector_type(4)));

// ---------------------------------------------------------------------------
// Kernel 1: P[r][h] = X[r] @ W1half (+ b1 for txt rows), bf16 MFMA, fp32 out.
// 544 tiles of 32m x 64n (2.1 blocks/CU), BK=64, register prefetch.
// LDS stride 72 bf16 = 36 dwords/row: 4-bank rotation per row -> every
// ds_write_b128 / ds_read_b128 phase is 2-way max = free (m136).
// Epilogue also accumulates pw[r] = 0.5*dot(P[r],W2) via shuffle+atomicAdd.
// ---------------------------------------------------------------------------
__global__ __launch_bounds__(256) void proj_kernel(
    const float* __restrict__ img, const float* __restrict__ txt,
    const float* __restrict__ W1, const float* __restrict__ b1,
    const float* __restrict__ W2, float* __restrict__ P,
    float* __restrict__ pw)
{
    __shared__ __align__(16) __bf16 As[32][72];
    __shared__ __align__(16) __bf16 Bs[64][72];

    const int tid = threadIdx.x;
    const int n0 = (blockIdx.x & 7) * 64;    // 8 n-tiles
    const int m0 = (blockIdx.x >> 3) * 32;   // 68 m-tiles
    const bool is_txt = (m0 >= N_IMG);
    const float* X  = is_txt ? (txt + (size_t)(m0 - N_IMG) * D_IN)
                             : (img + (size_t)m0 * D_IN);
    const float* Wb = W1 + (is_txt ? (size_t)D_IN * H_DIM : 0);

    const int wave = tid >> 6, lane = tid & 63;
    const int wm = (wave >> 1) * 16, wn = (wave & 1) * 32;
    const int quad = lane >> 4, lm = lane & 15;

    const int ar = tid >> 3, ak = (tid & 7) * 8;   // A: row ar, 8 floats at ak
    const int bn = tid & 63, bk = (tid >> 6) * 16; // B: col bn, 16 k at bk

    f32x4 acc[2] = {};
    f32x4 aR0, aR1;
    float bR[16];

    auto loadA = [&](int kc) {
        const float* ap = X + (size_t)ar * D_IN + kc + ak;
        aR0 = *(const f32x4*)(ap + 0);
        aR1 = *(const f32x4*)(ap + 4);
    };
    auto loadB = [&](int kc) {
        #pragma unroll
        for (int j = 0; j < 16; ++j)
            bR[j] = Wb[(size_t)(kc + bk + j) * H_DIM + n0 + bn];
    };

    union BPack { __bf16 h[8]; uint4 u; };

    loadA(0); loadB(0);

    for (int it = 0; it < 12; ++it) {
        BPack pa;
        #pragma unroll
        for (int j = 0; j < 4; ++j) { pa.h[j] = (__bf16)aR0[j]; pa.h[4+j] = (__bf16)aR1[j]; }
        *(uint4*)&As[ar][ak] = pa.u;
        BPack q0, q1;
        #pragma unroll
        for (int j = 0; j < 8; ++j) { q0.h[j] = (__bf16)bR[j]; q1.h[j] = (__bf16)bR[8+j]; }
        *(uint4*)&Bs[bn][bk]     = q0.u;
        *(uint4*)&Bs[bn][bk + 8] = q1.u;
        __syncthreads();

        if (it < 11) { loadA((it + 1) * 64); loadB((it + 1) * 64); }

        #pragma unroll
        for (int sub = 0; sub < 2; ++sub) {
            bf16x8 af  = *(bf16x8*)&As[wm + lm][sub * 32 + quad * 8];
            bf16x8 bf0 = *(bf16x8*)&Bs[wn +  0 + lm][sub * 32 + quad * 8];
            bf16x8 bf1 = *(bf16x8*)&Bs[wn + 16 + lm][sub * 32 + quad * 8];
            acc[0] = __builtin_amdgcn_mfma_f32_16x16x32_bf16(af, bf0, acc[0], 0, 0, 0);
            acc[1] = __builtin_amdgcn_mfma_f32_16x16x32_bf16(af, bf1, acc[1], 0, 0, 0);
        }
        __syncthreads();
    }

    // epilogue: C/D layout col=lane&15, row=quad*4+r [m89-verified];
    // write P and accumulate pw-row partials (0.5 * P . W2 over tile cols)
    float rv[4] = {0.f, 0.f, 0.f, 0.f};
    #pragma unroll
    for (int j = 0; j < 2; ++j) {
        const int gn = n0 + wn + j * 16 + lm;
        const float badd = is_txt ? b1[gn] : 0.0f;
        const float w2h = 0.5f * W2[gn];
        #pragma unroll
        for (int r = 0; r < 4; ++r) {
            const int gm = m0 + wm + quad * 4 + r;
            const float v = acc[j][r] + badd;
            P[(size_t)gm * H_DIM + gn] = v;
            rv[r] = fmaf(v, w2h, rv[r]);
        }
    }
    #pragma unroll
    for (int m = 1; m < 16; m <<= 1) {
        #pragma unroll
        for (int r = 0; r < 4; ++r) rv[r] += __shfl_xor(rv[r], m, 64);
    }
    if (lm == 0) {
        #pragma unroll
        for (int r = 0; r < 4; ++r)
            atomicAdd(&pw[m0 + wm + quad * 4 + r], rv[r]);
    }
}

// ---------------------------------------------------------------------------
// Kernel 2: P2[hs][n][k] = sum_{h in slab hs} |P_img[n,h] + P_txt[k,h]| * 0.5*W2[h]
// Tile 32n x 64k x 64h; grid 64x2x8 = 1024 blocks (4/CU). Plain f32x4 stores.
// Bs[64][67]: 4-row lane stride = 268 dwords = 12 mod 32 -> conflict-free.
// ---------------------------------------------------------------------------
__global__ __launch_bounds__(256) void sim_kernel(
    const float* __restrict__ P, const float* __restrict__ W2,
    float* __restrict__ P2)
{
    __shared__ __align__(16) float Bs[64][67];
    __shared__ __align__(16) float Ws[64];

    const int tid = threadIdx.x;
    const int n0 = blockIdx.x * 32;
    const int k0 = blockIdx.y * 64;
    const int hs = blockIdx.z;
    const int hc = hs * 64;

    #pragma unroll
    for (int i = 0; i < 4; ++i) {
        const int flat = tid + i * 256;
        const int row = flat >> 4, c4 = flat & 15;
        f32x4 v = *(const f32x4*)(P + (size_t)(N_IMG + k0 + row) * H_DIM + hc + c4 * 4);
        *(f32x4*)&Bs[row][c4 * 4] = v;
    }
    if (tid < 16) {
        f32x4 w = *(const f32x4*)(W2 + hc + tid * 4);
        w *= 0.5f;
        *(f32x4*)&Ws[tid * 4] = w;
    }
    __syncthreads();

    const int tx = tid & 15;   // k: 4 consecutive
    const int ty = tid >> 4;   // n: 2 consecutive rows
    const float* pA = P + (size_t)(n0 + ty * 2) * H_DIM + hc;

    f32x4 acc0 = {0.f, 0.f, 0.f, 0.f};
    f32x4 acc1 = {0.f, 0.f, 0.f, 0.f};

    #pragma unroll 4
    for (int h4 = 0; h4 < 16; ++h4) {
        f32x4 a0 = *(const f32x4*)(pA + h4 * 4);
        f32x4 a1 = *(const f32x4*)(pA + H_DIM + h4 * 4);
        f32x4 w  = *(f32x4*)&Ws[h4 * 4];
        f32x4 b[4];
        #pragma unroll
        for (int j = 0; j < 4; ++j) b[j] = *(f32x4*)&Bs[tx * 4 + j][h4 * 4];

        #pragma unroll
        for (int j = 0; j < 4; ++j) {
            #pragma unroll
            for (int hh = 0; hh < 4; ++hh) {
                const float t0 = a0[hh] + b[j][hh];
                acc0[j] = fmaf(fabsf(t0), w[hh], acc0[j]);
                const float t1 = a1[hh] + b[j][hh];
                acc1[j] = fmaf(fabsf(t1), w[hh], acc1[j]);
            }
        }
    }

    float* o = P2 + (size_t)hs * NK + (size_t)(n0 + ty * 2) * K_TXT + k0 + tx * 4;
    *(f32x4*)o = acc0;
    *(f32x4*)(o + K_TXT) = acc1;
}

// ---------------------------------------------------------------------------
// Kernel 3: out[n,k] = pw[n] + pw[N+k] + b2 + sum_{hs<8} P2[hs][n][k]
// ---------------------------------------------------------------------------
__global__ __launch_bounds__(256) void reduce_kernel(
    const float* __restrict__ P2, const float* __restrict__ pw,
    const float* __restrict__ b2, float* __restrict__ out)
{
    const int idx = blockIdx.x * 256 + threadIdx.x;   // f32x4 index, 65536 total
    const int n  = idx >> 5;
    const int k4 = (idx & 31) * 4;
    const size_t base = (size_t)n * K_TXT + k4;

    f32x4 s = {0.f, 0.f, 0.f, 0.f};
    #pragma unroll
    for (int hs = 0; hs < 8; ++hs)
        s += *(const f32x4*)(P2 + (size_t)hs * NK + base);

    const float add = pw[n] + b2[0];
    f32x4 pk = *(const f32x4*)(pw + N_IMG + k4);
    s[0] += add + pk[0]; s[1] += add + pk[1];
    s[2] += add + pk[2]; s[3] += add + pk[3];
    *(f32x4*)(out + base) = s;
}

// ---------------------------------------------------------------------------
extern "C" void kernel_launch(void* const* d_in, const int* in_sizes, int n_in,
                              void* d_out, int out_size, void* d_ws, size_t ws_size,
                              hipStream_t stream) {
    const float* img = (const float*)d_in[0];
    const float* txt = (const float*)d_in[1];
    const float* W1  = (const float*)d_in[2];
    const float* b1  = (const float*)d_in[3];
    const float* W2  = (const float*)d_in[4];
    const float* b2  = (const float*)d_in[5];
    float* out = (float*)d_out;

    float* P  = (float*)d_ws;                 // 2176 x 512 fp32 = 4.46 MB
    float* pw = P + (size_t)M_TOT * H_DIM;    // 2176 fp32 (atomic-accumulated)
    float* P2 = pw + M_TOT;                   // 8 x 2048 x 128 fp32 = 8.4 MB

    hipMemsetAsync(pw, 0, M_TOT * sizeof(float), stream);

    proj_kernel  <<<dim3(544),                256, 0, stream>>>(img, txt, W1, b1, W2, P, pw);
    sim_kernel   <<<dim3(N_IMG / 32, K_TXT / 64, H_DIM / 64), 256, 0, stream>>>(P, W2, P2);
    reduce_kernel<<<dim3(NK / 4 / 256),       256, 0, stream>>>(P2, pw, b2, out);
}

// Round 5
// 100.610 us; speedup vs baseline: 1.2691x; 1.0107x over previous
//
#include <hip/hip_runtime.h>
#include <hip/hip_bf16.h>

#define N_IMG 2048
#define K_TXT 128
#define D_IN  768
#define H_DIM 512
#define M_TOT (N_IMG + K_TXT)   // 2176 virtual rows (img ++ txt)
#define NK    (N_IMG * K_TXT)   // 262144 outputs
#define NTILE 16                // proj n-tiles (32 cols each)

typedef __bf16 bf16x8 __attribute__((ext_vector_type(8)));
typedef float  f32x4  __attribute__((ext_vector_type(4)));

// ---------------------------------------------------------------------------
// Kernel 1: P[r][h] = X[r] @ W1half (+ b1 for txt rows), bf16 MFMA, fp32 out.
// 1088 tiles of 32m x 32n (4.25 blocks/CU), BK=64, register prefetch.
// LDS stride 72 bf16 = 36 dwords/row: every ds_write_b128/ds_read_b128 phase
// is 2-way max = free (m136). Epilogue reduces pw-row partials across the
// block's 4 waves in LDS and writes deterministic slices pw2[ntile][row]
// (no atomics, no memset prerequisite).
// ---------------------------------------------------------------------------
__global__ __launch_bounds__(256) void proj_kernel(
    const float* __restrict__ img, const float* __restrict__ txt,
    const float* __restrict__ W1, const float* __restrict__ b1,
    const float* __restrict__ W2, float* __restrict__ P,
    float* __restrict__ pw2)
{
    __shared__ __align__(16) __bf16 As[32][72];
    __shared__ __align__(16) __bf16 Bs[32][72];
    __shared__ float lds_pw[32];

    const int tid = threadIdx.x;
    const int n0 = (blockIdx.x & (NTILE - 1)) * 32;  // 16 n-tiles
    const int m0 = (blockIdx.x >> 4) * 32;           // 68 m-tiles
    const bool is_txt = (m0 >= N_IMG);
    const float* X  = is_txt ? (txt + (size_t)(m0 - N_IMG) * D_IN)
                             : (img + (size_t)m0 * D_IN);
    const float* Wb = W1 + (is_txt ? (size_t)D_IN * H_DIM : 0);

    const int wave = tid >> 6, lane = tid & 63;
    const int wm = (wave >> 1) * 16, wn = (wave & 1) * 16;
    const int quad = lane >> 4, lm = lane & 15;

    const int ar = tid >> 3, ak = (tid & 7) * 8;   // A: row ar, 8 floats at ak
    const int bn = tid & 31, bk = (tid >> 5) * 8;  // B: col bn, 8 k at bk

    f32x4 acc = {0.f, 0.f, 0.f, 0.f};
    f32x4 aR0, aR1;
    float bR[8];

    auto loadA = [&](int kc) {
        const float* ap = X + (size_t)ar * D_IN + kc + ak;
        aR0 = *(const f32x4*)(ap + 0);
        aR1 = *(const f32x4*)(ap + 4);
    };
    auto loadB = [&](int kc) {
        #pragma unroll
        for (int j = 0; j < 8; ++j)
            bR[j] = Wb[(size_t)(kc + bk + j) * H_DIM + n0 + bn];
    };

    union BPack { __bf16 h[8]; uint4 u; };

    loadA(0); loadB(0);

    for (int it = 0; it < 12; ++it) {
        BPack pa;
        #pragma unroll
        for (int j = 0; j < 4; ++j) { pa.h[j] = (__bf16)aR0[j]; pa.h[4+j] = (__bf16)aR1[j]; }
        *(uint4*)&As[ar][ak] = pa.u;
        BPack q;
        #pragma unroll
        for (int j = 0; j < 8; ++j) q.h[j] = (__bf16)bR[j];
        *(uint4*)&Bs[bn][bk] = q.u;
        __syncthreads();

        if (it < 11) { loadA((it + 1) * 64); loadB((it + 1) * 64); }

        #pragma unroll
        for (int sub = 0; sub < 2; ++sub) {
            bf16x8 af = *(bf16x8*)&As[wm + lm][sub * 32 + quad * 8];
            bf16x8 bf = *(bf16x8*)&Bs[wn + lm][sub * 32 + quad * 8];
            acc = __builtin_amdgcn_mfma_f32_16x16x32_bf16(af, bf, acc, 0, 0, 0);
        }
        __syncthreads();
    }

    // epilogue: C/D layout col=lane&15, row=quad*4+r [m89-verified];
    // write P and accumulate pw-row partials (0.5 * P . W2 over tile cols)
    float rv[4];
    {
        const int gn = n0 + wn + lm;
        const float badd = is_txt ? b1[gn] : 0.0f;
        const float w2h = 0.5f * W2[gn];
        #pragma unroll
        for (int r = 0; r < 4; ++r) {
            const int gm = m0 + wm + quad * 4 + r;
            const float v = acc[r] + badd;
            P[(size_t)gm * H_DIM + gn] = v;
            rv[r] = v * w2h;
        }
    }
    #pragma unroll
    for (int m = 1; m < 16; m <<= 1) {
        #pragma unroll
        for (int r = 0; r < 4; ++r) rv[r] += __shfl_xor(rv[r], m, 64);
    }
    // combine the 2 wn-halves per row across waves via LDS
    if (tid < 32) lds_pw[tid] = 0.f;
    __syncthreads();
    if (lm == 0) {
        #pragma unroll
        for (int r = 0; r < 4; ++r)
            atomicAdd(&lds_pw[wm + quad * 4 + r], rv[r]);
    }
    __syncthreads();
    if (tid < 32)
        pw2[(size_t)(blockIdx.x & (NTILE - 1)) * M_TOT + m0 + tid] = lds_pw[tid];
}

// ---------------------------------------------------------------------------
// Kernel 2: P2[hs][n][k] = sum_{h in slab hs} |P_img[n,h] + P_txt[k,h]| * 0.5*W2[h]
// Tile 32n x 64k x 64h; grid 64x2x8 = 1024 blocks (4/CU). Plain f32x4 stores.
// Bs[64][67]: 4-row lane stride = 268 dwords = 12 mod 32 -> conflict-free.
// ---------------------------------------------------------------------------
__global__ __launch_bounds__(256) void sim_kernel(
    const float* __restrict__ P, const float* __restrict__ W2,
    float* __restrict__ P2)
{
    __shared__ __align__(16) float Bs[64][67];
    __shared__ __align__(16) float Ws[64];

    const int tid = threadIdx.x;
    const int n0 = blockIdx.x * 32;
    const int k0 = blockIdx.y * 64;
    const int hs = blockIdx.z;
    const int hc = hs * 64;

    #pragma unroll
    for (int i = 0; i < 4; ++i) {
        const int flat = tid + i * 256;
        const int row = flat >> 4, c4 = flat & 15;
        f32x4 v = *(const f32x4*)(P + (size_t)(N_IMG + k0 + row) * H_DIM + hc + c4 * 4);
        *(f32x4*)&Bs[row][c4 * 4] = v;
    }
    if (tid < 16) {
        f32x4 w = *(const f32x4*)(W2 + hc + tid * 4);
        w *= 0.5f;
        *(f32x4*)&Ws[tid * 4] = w;
    }
    __syncthreads();

    const int tx = tid & 15;   // k: 4 consecutive
    const int ty = tid >> 4;   // n: 2 consecutive rows
    const float* pA = P + (size_t)(n0 + ty * 2) * H_DIM + hc;

    f32x4 acc0 = {0.f, 0.f, 0.f, 0.f};
    f32x4 acc1 = {0.f, 0.f, 0.f, 0.f};

    #pragma unroll 4
    for (int h4 = 0; h4 < 16; ++h4) {
        f32x4 a0 = *(const f32x4*)(pA + h4 * 4);
        f32x4 a1 = *(const f32x4*)(pA + H_DIM + h4 * 4);
        f32x4 w  = *(f32x4*)&Ws[h4 * 4];
        f32x4 b[4];
        #pragma unroll
        for (int j = 0; j < 4; ++j) b[j] = *(f32x4*)&Bs[tx * 4 + j][h4 * 4];

        #pragma unroll
        for (int j = 0; j < 4; ++j) {
            #pragma unroll
            for (int hh = 0; hh < 4; ++hh) {
                const float t0 = a0[hh] + b[j][hh];
                acc0[j] = fmaf(fabsf(t0), w[hh], acc0[j]);
                const float t1 = a1[hh] + b[j][hh];
                acc1[j] = fmaf(fabsf(t1), w[hh], acc1[j]);
            }
        }
    }

    float* o = P2 + (size_t)hs * NK + (size_t)(n0 + ty * 2) * K_TXT + k0 + tx * 4;
    *(f32x4*)o = acc0;
    *(f32x4*)(o + K_TXT) = acc1;
}

// ---------------------------------------------------------------------------
// Kernel 3: out[n,k] = pw[n] + pw[N+k] + b2 + sum_{hs<8} P2[hs][n][k]
// where pw[r] = sum_{s<16} pw2[s][r]  (L2-resident slice reads)
// ---------------------------------------------------------------------------
__global__ __launch_bounds__(256) void reduce_kernel(
    const float* __restrict__ P2, const float* __restrict__ pw2,
    const float* __restrict__ b2, float* __restrict__ out)
{
    const int idx = blockIdx.x * 256 + threadIdx.x;   // f32x4 index, 65536 total
    const int n  = idx >> 5;
    const int k4 = (idx & 31) * 4;
    const size_t base = (size_t)n * K_TXT + k4;

    f32x4 s = {0.f, 0.f, 0.f, 0.f};
    #pragma unroll
    for (int hs = 0; hs < 8; ++hs)
        s += *(const f32x4*)(P2 + (size_t)hs * NK + base);

    float pn = 0.f;
    f32x4 pk = {0.f, 0.f, 0.f, 0.f};
    #pragma unroll
    for (int sl = 0; sl < NTILE; ++sl) {
        const float* pws = pw2 + (size_t)sl * M_TOT;
        pn += pws[n];
        pk += *(const f32x4*)(pws + N_IMG + k4);
    }

    const float add = pn + b2[0];
    s[0] += add + pk[0]; s[1] += add + pk[1];
    s[2] += add + pk[2]; s[3] += add + pk[3];
    *(f32x4*)(out + base) = s;
}

// ---------------------------------------------------------------------------
extern "C" void kernel_launch(void* const* d_in, const int* in_sizes, int n_in,
                              void* d_out, int out_size, void* d_ws, size_t ws_size,
                              hipStream_t stream) {
    const float* img = (const float*)d_in[0];
    const float* txt = (const float*)d_in[1];
    const float* W1  = (const float*)d_in[2];
    const float* b1  = (const float*)d_in[3];
    const float* W2  = (const float*)d_in[4];
    const float* b2  = (const float*)d_in[5];
    float* out = (float*)d_out;

    float* P   = (float*)d_ws;                  // 2176 x 512 fp32 = 4.46 MB
    float* pw2 = P + (size_t)M_TOT * H_DIM;     // 16 x 2176 fp32 (deterministic slices)
    float* P2  = pw2 + (size_t)NTILE * M_TOT;   // 8 x 2048 x 128 fp32 = 8.4 MB

    proj_kernel  <<<dim3(68 * NTILE),           256, 0, stream>>>(img, txt, W1, b1, W2, P, pw2);
    sim_kernel   <<<dim3(N_IMG / 32, K_TXT / 64, H_DIM / 64), 256, 0, stream>>>(P, W2, P2);
    reduce_kernel<<<dim3(NK / 4 / 256),         256, 0, stream>>>(P2, pw2, b2, out);
}